// Round 1
// baseline (1304.706 us; speedup 1.0000x reference)
//
#include <hip/hip_runtime.h>
#include <math.h>

#define F_IN 128
#define C1 256   // HEADS*HID
#define NH1 4
#define C2 64

__device__ __forceinline__ float lrelu(float x) { return x >= 0.f ? x : 0.2f * x; }

// h1[N,256] = x[N,128] @ W1[128,256]
__global__ __launch_bounds__(256) void k_gemm1(const float* __restrict__ x,
                                               const float* __restrict__ W,
                                               float* __restrict__ h1, int N) {
    __shared__ float xs[8][F_IN];
    int rowBase = blockIdx.x * 8;
    int t = threadIdx.x;
    for (int i = t; i < 8 * F_IN; i += 256) {
        int r = i >> 7, k = i & 127;
        int row = rowBase + r;
        xs[r][k] = (row < N) ? x[(size_t)row * F_IN + k] : 0.f;
    }
    __syncthreads();
    float acc[8] = {};
#pragma unroll 4
    for (int k = 0; k < F_IN; ++k) {
        float w = W[k * C1 + t];
#pragma unroll
        for (int r = 0; r < 8; ++r) acc[r] += xs[r][k] * w;
    }
    for (int r = 0; r < 8; ++r) {
        int row = rowBase + r;
        if (row < N) h1[(size_t)row * C1 + t] = acc[r];
    }
}

// per-node, per-head attention score halves: sS[n,h]=dot(h1[n,h,:],aS[h,:]) etc.
__global__ __launch_bounds__(256) void k_scores1(const float* __restrict__ h1,
                                                 const float* __restrict__ aS,
                                                 const float* __restrict__ aD,
                                                 float* __restrict__ sS,
                                                 float* __restrict__ sD, int N) {
    int n = blockIdx.x;
    int t = threadIdx.x;
    int h = t >> 6, c = t & 63;
    float v = h1[(size_t)n * C1 + t];
    float ps = v * aS[t];
    float pd = v * aD[t];
    for (int off = 32; off; off >>= 1) {
        ps += __shfl_down(ps, off, 64);
        pd += __shfl_down(pd, off, 64);
    }
    if (c == 0) { sS[n * NH1 + h] = ps; sD[n * NH1 + h] = pd; }
}

__global__ void k_edge_denom1(const int* __restrict__ esrc, const int* __restrict__ edst,
                              const float* __restrict__ sS, const float* __restrict__ sD,
                              float* __restrict__ denom, int E, int N) {
    int e = blockIdx.x * blockDim.x + threadIdx.x;
    int ET = E + N;
    if (e >= ET) return;
    int s, d;
    if (e < E) { s = esrc[e]; d = edst[e]; } else { s = d = e - E; }
    float4 a = *reinterpret_cast<const float4*>(sS + (size_t)s * 4);
    float4 b = *reinterpret_cast<const float4*>(sD + (size_t)d * 4);
    atomicAdd(&denom[d * 4 + 0], expf(lrelu(a.x + b.x)));
    atomicAdd(&denom[d * 4 + 1], expf(lrelu(a.y + b.y)));
    atomicAdd(&denom[d * 4 + 2], expf(lrelu(a.z + b.z)));
    atomicAdd(&denom[d * 4 + 3], expf(lrelu(a.w + b.w)));
}

// one block (256 thr) per edge; thread t = channel t (head = t>>6)
__global__ __launch_bounds__(256) void k_edge_aggr1(const int* __restrict__ esrc,
                                                    const int* __restrict__ edst,
                                                    const float* __restrict__ sS,
                                                    const float* __restrict__ sD,
                                                    const float* __restrict__ denom,
                                                    const float* __restrict__ h1,
                                                    float* __restrict__ out1, int E, int N) {
    int e = blockIdx.x;
    int s, d;
    if (e < E) { s = esrc[e]; d = edst[e]; } else { s = d = e - E; }
    int t = threadIdx.x;
    int h = t >> 6;
    float sc = lrelu(sS[s * 4 + h] + sD[d * 4 + h]);
    float alpha = expf(sc) / (denom[d * 4 + h] + 1e-16f);
    atomicAdd(&out1[(size_t)d * C1 + t], alpha * h1[(size_t)s * C1 + t]);
}

__global__ void k_finish1(float* __restrict__ out1, const float* __restrict__ b1, long total) {
    long i = (long)blockIdx.x * blockDim.x + threadIdx.x;
    if (i >= total) return;
    float v = out1[i] + b1[i & (C1 - 1)];
    out1[i] = v > 0.f ? v : expm1f(v);
}

// h2[N,64] = out1'[N,256] @ W2[256,64]
__global__ __launch_bounds__(256) void k_gemm2(const float* __restrict__ in,
                                               const float* __restrict__ W,
                                               float* __restrict__ h2, int N) {
    __shared__ float xs[16][C1];
    int rowBase = blockIdx.x * 16;
    int t = threadIdx.x;
    for (int i = t; i < 16 * C1; i += 256) {
        int r = i >> 8, k = i & 255;
        int row = rowBase + r;
        xs[r][k] = (row < N) ? in[(size_t)row * C1 + k] : 0.f;
    }
    __syncthreads();
    int j = t & 63, g = t >> 6;
    float acc[4] = {};
    for (int k = 0; k < C1; ++k) {
        float w = W[k * C2 + j];
#pragma unroll
        for (int r = 0; r < 4; ++r) acc[r] += xs[g * 4 + r][k] * w;
    }
    for (int r = 0; r < 4; ++r) {
        int row = rowBase + g * 4 + r;
        if (row < N) h2[(size_t)row * C2 + j] = acc[r];
    }
}

__global__ __launch_bounds__(256) void k_scores2(const float* __restrict__ h2,
                                                 const float* __restrict__ aS,
                                                 const float* __restrict__ aD,
                                                 float* __restrict__ sS,
                                                 float* __restrict__ sD, int N) {
    int n = blockIdx.x * 4 + (threadIdx.x >> 6);
    if (n >= N) return;
    int c = threadIdx.x & 63;
    float v = h2[(size_t)n * C2 + c];
    float ps = v * aS[c], pd = v * aD[c];
    for (int off = 32; off; off >>= 1) {
        ps += __shfl_down(ps, off, 64);
        pd += __shfl_down(pd, off, 64);
    }
    if (c == 0) { sS[n] = ps; sD[n] = pd; }
}

__global__ void k_edge_denom2(const int* __restrict__ esrc, const int* __restrict__ edst,
                              const float* __restrict__ sS, const float* __restrict__ sD,
                              float* __restrict__ denom, int E, int N) {
    int e = blockIdx.x * blockDim.x + threadIdx.x;
    int ET = E + N;
    if (e >= ET) return;
    int s, d;
    if (e < E) { s = esrc[e]; d = edst[e]; } else { s = d = e - E; }
    atomicAdd(&denom[d], expf(lrelu(sS[s] + sD[d])));
}

// 4 edges per 256-thread block (one wave per edge)
__global__ __launch_bounds__(256) void k_edge_aggr2(const int* __restrict__ esrc,
                                                    const int* __restrict__ edst,
                                                    const float* __restrict__ sS,
                                                    const float* __restrict__ sD,
                                                    const float* __restrict__ denom,
                                                    const float* __restrict__ h2,
                                                    float* __restrict__ out2, int E, int N) {
    int e = blockIdx.x * 4 + (threadIdx.x >> 6);
    int ET = E + N;
    if (e >= ET) return;
    int s, d;
    if (e < E) { s = esrc[e]; d = edst[e]; } else { s = d = e - E; }
    int c = threadIdx.x & 63;
    float sc = lrelu(sS[s] + sD[d]);
    float alpha = expf(sc) / (denom[d] + 1e-16f);
    atomicAdd(&out2[(size_t)d * C2 + c], alpha * h2[(size_t)s * C2 + c]);
}

// out[n,0:2] = (out2[n,:] + b2) @ Wc + bc
__global__ __launch_bounds__(256) void k_final(const float* __restrict__ out2,
                                               const float* __restrict__ b2,
                                               const float* __restrict__ Wc,
                                               const float* __restrict__ bc,
                                               float* __restrict__ out, int N) {
    int n = blockIdx.x * 4 + (threadIdx.x >> 6);
    if (n >= N) return;
    int c = threadIdx.x & 63;
    float v = out2[(size_t)n * C2 + c] + b2[c];
    float p0 = v * Wc[c * 2 + 0], p1 = v * Wc[c * 2 + 1];
    for (int off = 32; off; off >>= 1) {
        p0 += __shfl_down(p0, off, 64);
        p1 += __shfl_down(p1, off, 64);
    }
    if (c == 0) { out[n * 2 + 0] = p0 + bc[0]; out[n * 2 + 1] = p1 + bc[1]; }
}

extern "C" void kernel_launch(void* const* d_in, const int* in_sizes, int n_in,
                              void* d_out, int out_size, void* d_ws, size_t ws_size,
                              hipStream_t stream) {
    const float* x   = (const float*)d_in[0];
    const int*   ei  = (const int*)d_in[1];
    const float* W1  = (const float*)d_in[2];
    const float* aS1 = (const float*)d_in[3];
    const float* aD1 = (const float*)d_in[4];
    const float* b1  = (const float*)d_in[5];
    const float* W2  = (const float*)d_in[6];
    const float* aS2 = (const float*)d_in[7];
    const float* aD2 = (const float*)d_in[8];
    const float* b2  = (const float*)d_in[9];
    const float* Wc  = (const float*)d_in[10];
    const float* bc  = (const float*)d_in[11];
    float* out = (float*)d_out;

    int N = in_sizes[0] / F_IN;
    int E = in_sizes[1] / 2;
    const int* esrc = ei;
    const int* edst = ei + E;
    int ET = E + N;

    float* p = (float*)d_ws;
    float* h1   = p; p += (size_t)N * C1;
    float* s1S  = p; p += (size_t)N * NH1;
    float* s1D  = p; p += (size_t)N * NH1;
    float* den1 = p; p += (size_t)N * NH1;
    float* o1   = p; p += (size_t)N * C1;
    float* h2   = p; p += (size_t)N * C2;
    float* s2S  = p; p += N;
    float* s2D  = p; p += N;
    float* den2 = p; p += N;
    float* o2   = p; p += (size_t)N * C2;

    hipMemsetAsync(den1, 0, (size_t)N * NH1 * 4, stream);
    hipMemsetAsync(o1,   0, (size_t)N * C1 * 4, stream);
    hipMemsetAsync(den2, 0, (size_t)N * 4, stream);
    hipMemsetAsync(o2,   0, (size_t)N * C2 * 4, stream);

    k_gemm1<<<(N + 7) / 8, 256, 0, stream>>>(x, W1, h1, N);
    k_scores1<<<N, 256, 0, stream>>>(h1, aS1, aD1, s1S, s1D, N);
    k_edge_denom1<<<(ET + 255) / 256, 256, 0, stream>>>(esrc, edst, s1S, s1D, den1, E, N);
    k_edge_aggr1<<<ET, 256, 0, stream>>>(esrc, edst, s1S, s1D, den1, h1, o1, E, N);
    k_finish1<<<(int)(((long)N * C1 + 255) / 256), 256, 0, stream>>>(o1, b1, (long)N * C1);
    k_gemm2<<<(N + 15) / 16, 256, 0, stream>>>(o1, W2, h2, N);
    k_scores2<<<(N + 3) / 4, 256, 0, stream>>>(h2, aS2, aD2, s2S, s2D, N);
    k_edge_denom2<<<(ET + 255) / 256, 256, 0, stream>>>(esrc, edst, s2S, s2D, den2, E, N);
    k_edge_aggr2<<<(ET + 3) / 4, 256, 0, stream>>>(esrc, edst, s2S, s2D, den2, h2, o2, E, N);
    k_final<<<(N + 3) / 4, 256, 0, stream>>>(o2, b2, Wc, bc, out, N);
}

// Round 2
// 476.545 us; speedup vs baseline: 2.7378x; 2.7378x over previous
//
#include <hip/hip_runtime.h>
#include <math.h>

#define F_IN 128
#define C1 256   // HEADS*HID
#define NH1 4
#define C2 64
#define SCAN_CHUNK 512

__device__ __forceinline__ float lrelu(float x) { return x >= 0.f ? x : 0.2f * x; }
__device__ __forceinline__ float elu(float x) { return x > 0.f ? x : expm1f(x); }

// ---------------- CSR build ----------------
__global__ void k_count(const int* __restrict__ edst, int* __restrict__ cnt, int E, int N) {
    int e = blockIdx.x * blockDim.x + threadIdx.x;
    int ET = E + N;
    if (e >= ET) return;
    int d = (e < E) ? edst[e] : (e - E);
    atomicAdd(&cnt[d], 1);
}

__global__ __launch_bounds__(SCAN_CHUNK) void k_scan_a(const int* __restrict__ cnt,
                                                        int* __restrict__ rs,
                                                        int* __restrict__ bsum, int N) {
    __shared__ int tmp[SCAN_CHUNK];
    int base = blockIdx.x * SCAN_CHUNK;
    int t = threadIdx.x;
    int v = (base + t < N) ? cnt[base + t] : 0;
    tmp[t] = v;
    __syncthreads();
    for (int off = 1; off < SCAN_CHUNK; off <<= 1) {
        int add = (t >= off) ? tmp[t - off] : 0;
        __syncthreads();
        tmp[t] += add;
        __syncthreads();
    }
    if (base + t < N) rs[base + t] = tmp[t] - v;  // exclusive within block
    if (t == SCAN_CHUNK - 1) bsum[blockIdx.x] = tmp[t];
}

__global__ void k_scan_b(int* __restrict__ bsum, int nb, int* __restrict__ total_out) {
    if (threadIdx.x == 0 && blockIdx.x == 0) {
        int acc = 0;
        for (int i = 0; i < nb; ++i) { int v = bsum[i]; bsum[i] = acc; acc += v; }
        *total_out = acc;   // rs[N]
    }
}

__global__ void k_scan_c(int* __restrict__ rs, const int* __restrict__ bsum, int N) {
    int i = blockIdx.x * blockDim.x + threadIdx.x;
    if (i < N) rs[i] += bsum[i / SCAN_CHUNK];
}

// elist[slot] = src node id, bucketed by dst
__global__ void k_scatter(const int* __restrict__ esrc, const int* __restrict__ edst,
                          const int* __restrict__ rs, int* __restrict__ cursor,
                          int* __restrict__ elist, int E, int N) {
    int e = blockIdx.x * blockDim.x + threadIdx.x;
    int ET = E + N;
    if (e >= ET) return;
    int s, d;
    if (e < E) { s = esrc[e]; d = edst[e]; } else { s = d = e - E; }
    int pos = atomicAdd(&cursor[d], 1);
    elist[rs[d] + pos] = s;
}

// ---------------- layer compute ----------------
// h1[N,256] = x[N,128] @ W1[128,256]
__global__ __launch_bounds__(256) void k_gemm1(const float* __restrict__ x,
                                               const float* __restrict__ W,
                                               float* __restrict__ h1, int N) {
    __shared__ float xs[8][F_IN];
    int rowBase = blockIdx.x * 8;
    int t = threadIdx.x;
    for (int i = t; i < 8 * F_IN; i += 256) {
        int r = i >> 7, k = i & 127;
        int row = rowBase + r;
        xs[r][k] = (row < N) ? x[(size_t)row * F_IN + k] : 0.f;
    }
    __syncthreads();
    float acc[8] = {};
#pragma unroll 4
    for (int k = 0; k < F_IN; ++k) {
        float w = W[k * C1 + t];
#pragma unroll
        for (int r = 0; r < 8; ++r) acc[r] += xs[r][k] * w;
    }
    for (int r = 0; r < 8; ++r) {
        int row = rowBase + r;
        if (row < N) h1[(size_t)row * C1 + t] = acc[r];
    }
}

__global__ __launch_bounds__(256) void k_scores1(const float* __restrict__ h1,
                                                 const float* __restrict__ aS,
                                                 const float* __restrict__ aD,
                                                 float* __restrict__ sS,
                                                 float* __restrict__ sD, int N) {
    int n = blockIdx.x;
    int t = threadIdx.x;
    int h = t >> 6, c = t & 63;
    float v = h1[(size_t)n * C1 + t];
    float ps = v * aS[t];
    float pd = v * aD[t];
    for (int off = 32; off; off >>= 1) {
        ps += __shfl_down(ps, off, 64);
        pd += __shfl_down(pd, off, 64);
    }
    if (c == 0) { sS[n * NH1 + h] = ps; sD[n * NH1 + h] = pd; }
}

// one wave per dst node; lane covers 4 channels (float4). Fused: softmax denom,
// normalize, +b1, ELU. No atomics.
__global__ __launch_bounds__(256) void k_aggr1(const int* __restrict__ elist,
                                               const int* __restrict__ rs,
                                               const float* __restrict__ sS,
                                               const float* __restrict__ sD,
                                               const float* __restrict__ h1,
                                               const float* __restrict__ b1,
                                               float* __restrict__ o1, int N) {
    int d = blockIdx.x * 4 + (threadIdx.x >> 6);
    if (d >= N) return;
    int lane = threadIdx.x & 63;
    int h = lane >> 4;                 // channels 4*lane..4*lane+3 -> head lane/16
    float sdh = sD[d * 4 + h];
    int beg = rs[d], end = rs[d + 1];
    float4 acc = {0.f, 0.f, 0.f, 0.f};
    float den = 0.f;
    for (int i = beg; i < end; ++i) {
        int s = elist[i];
        float w = __expf(lrelu(sS[s * 4 + h] + sdh));
        den += w;
        float4 hv = *reinterpret_cast<const float4*>(h1 + (size_t)s * C1 + lane * 4);
        acc.x += w * hv.x; acc.y += w * hv.y; acc.z += w * hv.z; acc.w += w * hv.w;
    }
    float inv = 1.f / (den + 1e-16f);
    float4 bb = *reinterpret_cast<const float4*>(b1 + lane * 4);
    float4 o;
    o.x = elu(acc.x * inv + bb.x);
    o.y = elu(acc.y * inv + bb.y);
    o.z = elu(acc.z * inv + bb.z);
    o.w = elu(acc.w * inv + bb.w);
    *reinterpret_cast<float4*>(o1 + (size_t)d * C1 + lane * 4) = o;
}

// h2[N,64] = o1[N,256] @ W2[256,64]
__global__ __launch_bounds__(256) void k_gemm2(const float* __restrict__ in,
                                               const float* __restrict__ W,
                                               float* __restrict__ h2, int N) {
    __shared__ float xs[16][C1];
    int rowBase = blockIdx.x * 16;
    int t = threadIdx.x;
    for (int i = t; i < 16 * C1; i += 256) {
        int r = i >> 8, k = i & 255;
        int row = rowBase + r;
        xs[r][k] = (row < N) ? in[(size_t)row * C1 + k] : 0.f;
    }
    __syncthreads();
    int j = t & 63, g = t >> 6;
    float acc[4] = {};
    for (int k = 0; k < C1; ++k) {
        float w = W[k * C2 + j];
#pragma unroll
        for (int r = 0; r < 4; ++r) acc[r] += xs[g * 4 + r][k] * w;
    }
    for (int r = 0; r < 4; ++r) {
        int row = rowBase + g * 4 + r;
        if (row < N) h2[(size_t)row * C2 + j] = acc[r];
    }
}

__global__ __launch_bounds__(256) void k_scores2(const float* __restrict__ h2,
                                                 const float* __restrict__ aS,
                                                 const float* __restrict__ aD,
                                                 float* __restrict__ sS,
                                                 float* __restrict__ sD, int N) {
    int n = blockIdx.x * 4 + (threadIdx.x >> 6);
    if (n >= N) return;
    int c = threadIdx.x & 63;
    float v = h2[(size_t)n * C2 + c];
    float ps = v * aS[c], pd = v * aD[c];
    for (int off = 32; off; off >>= 1) {
        ps += __shfl_down(ps, off, 64);
        pd += __shfl_down(pd, off, 64);
    }
    if (c == 0) { sS[n] = ps; sD[n] = pd; }
}

// one wave per dst node; lane = channel. Fused: denom, normalize, +b2,
// classifier (64->2) + bc. Writes final output. No atomics.
__global__ __launch_bounds__(256) void k_aggr2(const int* __restrict__ elist,
                                               const int* __restrict__ rs,
                                               const float* __restrict__ sS,
                                               const float* __restrict__ sD,
                                               const float* __restrict__ h2,
                                               const float* __restrict__ b2,
                                               const float* __restrict__ Wc,
                                               const float* __restrict__ bc,
                                               float* __restrict__ out, int N) {
    int d = blockIdx.x * 4 + (threadIdx.x >> 6);
    if (d >= N) return;
    int c = threadIdx.x & 63;
    float sdd = sD[d];
    int beg = rs[d], end = rs[d + 1];
    float acc = 0.f, den = 0.f;
    for (int i = beg; i < end; ++i) {
        int s = elist[i];
        float w = __expf(lrelu(sS[s] + sdd));
        den += w;
        acc += w * h2[(size_t)s * C2 + c];
    }
    float v = acc / (den + 1e-16f) + b2[c];
    float p0 = v * Wc[c * 2 + 0], p1 = v * Wc[c * 2 + 1];
    for (int off = 32; off; off >>= 1) {
        p0 += __shfl_down(p0, off, 64);
        p1 += __shfl_down(p1, off, 64);
    }
    if (c == 0) { out[d * 2 + 0] = p0 + bc[0]; out[d * 2 + 1] = p1 + bc[1]; }
}

extern "C" void kernel_launch(void* const* d_in, const int* in_sizes, int n_in,
                              void* d_out, int out_size, void* d_ws, size_t ws_size,
                              hipStream_t stream) {
    const float* x   = (const float*)d_in[0];
    const int*   ei  = (const int*)d_in[1];
    const float* W1  = (const float*)d_in[2];
    const float* aS1 = (const float*)d_in[3];
    const float* aD1 = (const float*)d_in[4];
    const float* b1  = (const float*)d_in[5];
    const float* W2  = (const float*)d_in[6];
    const float* aS2 = (const float*)d_in[7];
    const float* aD2 = (const float*)d_in[8];
    const float* b2  = (const float*)d_in[9];
    const float* Wc  = (const float*)d_in[10];
    const float* bc  = (const float*)d_in[11];
    float* out = (float*)d_out;

    int N = in_sizes[0] / F_IN;
    int E = in_sizes[1] / 2;
    const int* esrc = ei;
    const int* edst = ei + E;
    int ET = E + N;
    int nb = (N + SCAN_CHUNK - 1) / SCAN_CHUNK;

    float* p = (float*)d_ws;
    float* h1   = p; p += (size_t)N * C1;
    float* o1   = p; p += (size_t)N * C1;
    float* h2   = p; p += (size_t)N * C2;
    float* s1S  = p; p += (size_t)N * NH1;
    float* s1D  = p; p += (size_t)N * NH1;
    float* s2S  = p; p += N;
    float* s2D  = p; p += N;
    int* cnt    = (int*)p; p += N;
    int* rs     = (int*)p; p += (N + 1);
    int* cursor = (int*)p; p += N;
    int* bsum   = (int*)p; p += nb;
    int* elist  = (int*)p; p += ET;

    // CSR build (shared by both layers)
    hipMemsetAsync(cnt, 0, (size_t)N * 4, stream);
    hipMemsetAsync(cursor, 0, (size_t)N * 4, stream);
    k_count<<<(ET + 255) / 256, 256, 0, stream>>>(edst, cnt, E, N);
    k_scan_a<<<nb, SCAN_CHUNK, 0, stream>>>(cnt, rs, bsum, N);
    k_scan_b<<<1, 64, 0, stream>>>(bsum, nb, rs + N);
    k_scan_c<<<(N + 255) / 256, 256, 0, stream>>>(rs, bsum, N);
    k_scatter<<<(ET + 255) / 256, 256, 0, stream>>>(esrc, edst, rs, cursor, elist, E, N);

    // layer 1
    k_gemm1<<<(N + 7) / 8, 256, 0, stream>>>(x, W1, h1, N);
    k_scores1<<<N, 256, 0, stream>>>(h1, aS1, aD1, s1S, s1D, N);
    k_aggr1<<<(N + 3) / 4, 256, 0, stream>>>(elist, rs, s1S, s1D, h1, b1, o1, N);

    // layer 2 + classifier
    k_gemm2<<<(N + 15) / 16, 256, 0, stream>>>(o1, W2, h2, N);
    k_scores2<<<(N + 3) / 4, 256, 0, stream>>>(h2, aS2, aD2, s2S, s2D, N);
    k_aggr2<<<(N + 3) / 4, 256, 0, stream>>>(elist, rs, s2S, s2D, h2, b2, Wc, bc, out, N);
}

// Round 3
// 411.459 us; speedup vs baseline: 3.1709x; 1.1582x over previous
//
#include <hip/hip_runtime.h>
#include <hip/hip_fp16.h>
#include <math.h>

#define F_IN 128
#define C1 256   // HEADS*HID
#define NH1 4
#define C2 64
#define SCAN_CHUNK 512

__device__ __forceinline__ float lrelu(float x) { return x >= 0.f ? x : 0.2f * x; }
__device__ __forceinline__ float elu(float x) { return x > 0.f ? x : expm1f(x); }

struct __align__(8) H4 { __half2 a, b; };

// ---------------- CSR build ----------------
__global__ void k_count(const int* __restrict__ edst, int* __restrict__ cnt, int E, int N) {
    int e = blockIdx.x * blockDim.x + threadIdx.x;
    int ET = E + N;
    if (e >= ET) return;
    int d = (e < E) ? edst[e] : (e - E);
    atomicAdd(&cnt[d], 1);
}

__global__ __launch_bounds__(SCAN_CHUNK) void k_scan_a(const int* __restrict__ cnt,
                                                        int* __restrict__ rs,
                                                        int* __restrict__ bsum, int N) {
    __shared__ int tmp[SCAN_CHUNK];
    int base = blockIdx.x * SCAN_CHUNK;
    int t = threadIdx.x;
    int v = (base + t < N) ? cnt[base + t] : 0;
    tmp[t] = v;
    __syncthreads();
    for (int off = 1; off < SCAN_CHUNK; off <<= 1) {
        int add = (t >= off) ? tmp[t - off] : 0;
        __syncthreads();
        tmp[t] += add;
        __syncthreads();
    }
    if (base + t < N) rs[base + t] = tmp[t] - v;  // exclusive within block
    if (t == SCAN_CHUNK - 1) bsum[blockIdx.x] = tmp[t];
}

__global__ void k_scan_b(int* __restrict__ bsum, int nb, int* __restrict__ total_out) {
    if (threadIdx.x == 0 && blockIdx.x == 0) {
        int acc = 0;
        for (int i = 0; i < nb; ++i) { int v = bsum[i]; bsum[i] = acc; acc += v; }
        *total_out = acc;   // rs[N]
    }
}

__global__ void k_scan_c(int* __restrict__ rs, const int* __restrict__ bsum, int N) {
    int i = blockIdx.x * blockDim.x + threadIdx.x;
    if (i < N) rs[i] += bsum[i / SCAN_CHUNK];
}

__global__ void k_scatter(const int* __restrict__ esrc, const int* __restrict__ edst,
                          const int* __restrict__ rs, int* __restrict__ cursor,
                          int* __restrict__ elist, int E, int N) {
    int e = blockIdx.x * blockDim.x + threadIdx.x;
    int ET = E + N;
    if (e >= ET) return;
    int s, d;
    if (e < E) { s = esrc[e]; d = edst[e]; } else { s = d = e - E; }
    int pos = atomicAdd(&cursor[d], 1);
    elist[rs[d] + pos] = s;
}

// ---------------- layer 1 GEMM (fused scores, fp16 message output) ----------------
// 64 rows/block, 256 threads, each thread 16 rows x 4 cols.
__global__ __launch_bounds__(256) void k_gemm1(const float* __restrict__ x,
                                               const float* __restrict__ W,
                                               const float* __restrict__ aS,
                                               const float* __restrict__ aD,
                                               __half* __restrict__ h1h,
                                               float* __restrict__ sS,
                                               float* __restrict__ sD, int N) {
    __shared__ float xsT[F_IN][64];   // transposed, row-rotated by 8*((k>>2)&7)
    int t = threadIdx.x;
    int rowBase = blockIdx.x * 64;
#pragma unroll
    for (int p = 0; p < 8; ++p) {
        int r = p * 8 + (t >> 5);
        int l = t & 31;
        int k4 = l * 4;
        int row = rowBase + r;
        float4 v = {0.f, 0.f, 0.f, 0.f};
        if (row < N) v = *(const float4*)(x + (size_t)row * F_IN + k4);
        int sw = (r + 8 * (l & 7)) & 63;
        xsT[k4 + 0][sw] = v.x; xsT[k4 + 1][sw] = v.y;
        xsT[k4 + 2][sw] = v.z; xsT[k4 + 3][sw] = v.w;
    }
    __syncthreads();
    int lane = t & 63, wv = t >> 6;
    int c = lane * 4;
    float acc[16][4] = {};
    for (int k = 0; k < F_IN; ++k) {
        float4 w = *(const float4*)(W + (size_t)k * C1 + c);
        int rot = 8 * ((k >> 2) & 7);
        float xr[16];
#pragma unroll
        for (int q = 0; q < 4; ++q) {
            int a = (wv * 16 + q * 4 + rot) & 63;
            float4 xv = *(const float4*)&xsT[k][a];
            xr[q * 4 + 0] = xv.x; xr[q * 4 + 1] = xv.y;
            xr[q * 4 + 2] = xv.z; xr[q * 4 + 3] = xv.w;
        }
#pragma unroll
        for (int r = 0; r < 16; ++r) {
            acc[r][0] += xr[r] * w.x; acc[r][1] += xr[r] * w.y;
            acc[r][2] += xr[r] * w.z; acc[r][3] += xr[r] * w.w;
        }
    }
    float4 as4 = *(const float4*)(aS + c);
    float4 ad4 = *(const float4*)(aD + c);
    int h = lane >> 4;
#pragma unroll
    for (int r = 0; r < 16; ++r) {
        int row = rowBase + wv * 16 + r;
        float a0 = acc[r][0], a1 = acc[r][1], a2 = acc[r][2], a3 = acc[r][3];
        float ps = a0 * as4.x + a1 * as4.y + a2 * as4.z + a3 * as4.w;
        float pd = a0 * ad4.x + a1 * ad4.y + a2 * ad4.z + a3 * ad4.w;
#pragma unroll
        for (int off = 1; off < 16; off <<= 1) {
            ps += __shfl_xor(ps, off, 64);
            pd += __shfl_xor(pd, off, 64);
        }
        if (row < N) {
            H4 hv;
            hv.a = __floats2half2_rn(a0, a1);
            hv.b = __floats2half2_rn(a2, a3);
            *(H4*)(h1h + (size_t)row * C1 + c) = hv;
            if ((lane & 15) == 0) { sS[row * 4 + h] = ps; sD[row * 4 + h] = pd; }
        }
    }
}

// one wave per dst node; lane covers 4 channels. fp16 gather, fused denom+b1+ELU.
__global__ __launch_bounds__(256) void k_aggr1(const int* __restrict__ elist,
                                               const int* __restrict__ rs,
                                               const float* __restrict__ sS,
                                               const float* __restrict__ sD,
                                               const __half* __restrict__ h1h,
                                               const float* __restrict__ b1,
                                               float* __restrict__ o1, int N) {
    int d = blockIdx.x * 4 + (threadIdx.x >> 6);
    if (d >= N) return;
    int lane = threadIdx.x & 63;
    int h = lane >> 4;
    float sdh = sD[d * 4 + h];
    int beg = rs[d], end = rs[d + 1];
    float4 acc = {0.f, 0.f, 0.f, 0.f};
    float den = 0.f;
    for (int i = beg; i < end; ++i) {
        int s = elist[i];
        float w = __expf(lrelu(sS[s * 4 + h] + sdh));
        den += w;
        float2 raw = *(const float2*)(h1h + (size_t)s * C1 + lane * 4);
        __half2 h01 = *(__half2*)&raw.x;
        __half2 h23 = *(__half2*)&raw.y;
        float2 f01 = __half22float2(h01), f23 = __half22float2(h23);
        acc.x += w * f01.x; acc.y += w * f01.y;
        acc.z += w * f23.x; acc.w += w * f23.y;
    }
    float inv = 1.f / (den + 1e-16f);
    float4 bb = *(const float4*)(b1 + lane * 4);
    float4 o;
    o.x = elu(acc.x * inv + bb.x);
    o.y = elu(acc.y * inv + bb.y);
    o.z = elu(acc.z * inv + bb.z);
    o.w = elu(acc.w * inv + bb.w);
    *reinterpret_cast<float4*>(o1 + (size_t)d * C1 + lane * 4) = o;
}

// ---------------- layer 2 GEMM (fused scores, fp16 message output) ----------------
// 128 rows/block, BK=64, 256 threads, each thread 8 rows x 4 cols.
__global__ __launch_bounds__(256) void k_gemm2(const float* __restrict__ o1,
                                               const float* __restrict__ W2,
                                               const float* __restrict__ aS,
                                               const float* __restrict__ aD,
                                               __half* __restrict__ h2h,
                                               float* __restrict__ sS,
                                               float* __restrict__ sD, int N) {
    __shared__ float xsT[64][128];   // transposed chunk, row-rotated by 8*((k>>2)&15)
    int t = threadIdx.x;
    int rowBase = blockIdx.x * 128;
    int cg = t & 15, rg = t >> 4;    // cols cg*4..+3, rows rg*8..+7
    float acc[8][4] = {};
    for (int kc = 0; kc < 4; ++kc) {
        __syncthreads();
#pragma unroll
        for (int p = 0; p < 8; ++p) {
            int idx = p * 256 + t;
            int r = idx >> 4;
            int li = idx & 15;
            int c4 = li * 4;
            int row = rowBase + r;
            float4 v = {0.f, 0.f, 0.f, 0.f};
            if (row < N) v = *(const float4*)(o1 + (size_t)row * C1 + kc * 64 + c4);
            int sw = (r + 8 * li) & 127;
            xsT[c4 + 0][sw] = v.x; xsT[c4 + 1][sw] = v.y;
            xsT[c4 + 2][sw] = v.z; xsT[c4 + 3][sw] = v.w;
        }
        __syncthreads();
        for (int k = 0; k < 64; ++k) {
            float4 w = *(const float4*)(W2 + (size_t)(kc * 64 + k) * C2 + cg * 4);
            int rot = 8 * ((k >> 2) & 15);
            float xr[8];
#pragma unroll
            for (int q = 0; q < 2; ++q) {
                int a = (rg * 8 + q * 4 + rot) & 127;
                float4 xv = *(const float4*)&xsT[k][a];
                xr[q * 4 + 0] = xv.x; xr[q * 4 + 1] = xv.y;
                xr[q * 4 + 2] = xv.z; xr[q * 4 + 3] = xv.w;
            }
#pragma unroll
            for (int r = 0; r < 8; ++r) {
                acc[r][0] += xr[r] * w.x; acc[r][1] += xr[r] * w.y;
                acc[r][2] += xr[r] * w.z; acc[r][3] += xr[r] * w.w;
            }
        }
    }
    float4 as4 = *(const float4*)(aS + cg * 4);
    float4 ad4 = *(const float4*)(aD + cg * 4);
#pragma unroll
    for (int r = 0; r < 8; ++r) {
        int row = rowBase + rg * 8 + r;
        float a0 = acc[r][0], a1 = acc[r][1], a2 = acc[r][2], a3 = acc[r][3];
        float ps = a0 * as4.x + a1 * as4.y + a2 * as4.z + a3 * as4.w;
        float pd = a0 * ad4.x + a1 * ad4.y + a2 * ad4.z + a3 * ad4.w;
#pragma unroll
        for (int off = 1; off < 16; off <<= 1) {
            ps += __shfl_xor(ps, off, 64);
            pd += __shfl_xor(pd, off, 64);
        }
        if (row < N) {
            H4 hv;
            hv.a = __floats2half2_rn(a0, a1);
            hv.b = __floats2half2_rn(a2, a3);
            *(H4*)(h2h + (size_t)row * C2 + cg * 4) = hv;
            if (cg == 0) { sS[row] = ps; sD[row] = pd; }
        }
    }
}

// one wave per dst node; lane = channel. fp16 gather; fused denom + b2 + classifier.
__global__ __launch_bounds__(256) void k_aggr2(const int* __restrict__ elist,
                                               const int* __restrict__ rs,
                                               const float* __restrict__ sS,
                                               const float* __restrict__ sD,
                                               const __half* __restrict__ h2h,
                                               const float* __restrict__ b2,
                                               const float* __restrict__ Wc,
                                               const float* __restrict__ bc,
                                               float* __restrict__ out, int N) {
    int d = blockIdx.x * 4 + (threadIdx.x >> 6);
    if (d >= N) return;
    int c = threadIdx.x & 63;
    float sdd = sD[d];
    int beg = rs[d], end = rs[d + 1];
    float acc = 0.f, den = 0.f;
    for (int i = beg; i < end; ++i) {
        int s = elist[i];
        float w = __expf(lrelu(sS[s] + sdd));
        den += w;
        acc += w * __half2float(h2h[(size_t)s * C2 + c]);
    }
    float v = acc / (den + 1e-16f) + b2[c];
    float p0 = v * Wc[c * 2 + 0], p1 = v * Wc[c * 2 + 1];
    for (int off = 32; off; off >>= 1) {
        p0 += __shfl_down(p0, off, 64);
        p1 += __shfl_down(p1, off, 64);
    }
    if (c == 0) { out[d * 2 + 0] = p0 + bc[0]; out[d * 2 + 1] = p1 + bc[1]; }
}

extern "C" void kernel_launch(void* const* d_in, const int* in_sizes, int n_in,
                              void* d_out, int out_size, void* d_ws, size_t ws_size,
                              hipStream_t stream) {
    const float* x   = (const float*)d_in[0];
    const int*   ei  = (const int*)d_in[1];
    const float* W1  = (const float*)d_in[2];
    const float* aS1 = (const float*)d_in[3];
    const float* aD1 = (const float*)d_in[4];
    const float* b1  = (const float*)d_in[5];
    const float* W2  = (const float*)d_in[6];
    const float* aS2 = (const float*)d_in[7];
    const float* aD2 = (const float*)d_in[8];
    const float* b2  = (const float*)d_in[9];
    const float* Wc  = (const float*)d_in[10];
    const float* bc  = (const float*)d_in[11];
    float* out = (float*)d_out;

    int N = in_sizes[0] / F_IN;
    int E = in_sizes[1] / 2;
    const int* esrc = ei;
    const int* edst = ei + E;
    int ET = E + N;
    int nb = (N + SCAN_CHUNK - 1) / SCAN_CHUNK;

    char* p = (char*)d_ws;
    __half* h1h = (__half*)p; p += (size_t)N * C1 * sizeof(__half);
    __half* h2h = (__half*)p; p += (size_t)N * C2 * sizeof(__half);
    float* o1   = (float*)p;  p += (size_t)N * C1 * sizeof(float);
    float* s1S  = (float*)p;  p += (size_t)N * NH1 * sizeof(float);
    float* s1D  = (float*)p;  p += (size_t)N * NH1 * sizeof(float);
    float* s2S  = (float*)p;  p += (size_t)N * sizeof(float);
    float* s2D  = (float*)p;  p += (size_t)N * sizeof(float);
    int* cnt    = (int*)p;    p += (size_t)N * sizeof(int);
    int* rs     = (int*)p;    p += (size_t)(N + 1) * sizeof(int);
    int* cursor = (int*)p;    p += (size_t)N * sizeof(int);
    int* bsum   = (int*)p;    p += (size_t)nb * sizeof(int);
    int* elist  = (int*)p;    p += (size_t)ET * sizeof(int);

    // CSR build (shared by both layers)
    hipMemsetAsync(cnt, 0, (size_t)N * 4, stream);
    hipMemsetAsync(cursor, 0, (size_t)N * 4, stream);
    k_count<<<(ET + 255) / 256, 256, 0, stream>>>(edst, cnt, E, N);
    k_scan_a<<<nb, SCAN_CHUNK, 0, stream>>>(cnt, rs, bsum, N);
    k_scan_b<<<1, 64, 0, stream>>>(bsum, nb, rs + N);
    k_scan_c<<<(N + 255) / 256, 256, 0, stream>>>(rs, bsum, N);
    k_scatter<<<(ET + 255) / 256, 256, 0, stream>>>(esrc, edst, rs, cursor, elist, E, N);

    // layer 1
    k_gemm1<<<(N + 63) / 64, 256, 0, stream>>>(x, W1, aS1, aD1, h1h, s1S, s1D, N);
    k_aggr1<<<(N + 3) / 4, 256, 0, stream>>>(elist, rs, s1S, s1D, h1h, b1, o1, N);

    // layer 2 + classifier
    k_gemm2<<<(N + 127) / 128, 256, 0, stream>>>(o1, W2, aS2, aD2, h2h, s2S, s2D, N);
    k_aggr2<<<(N + 3) / 4, 256, 0, stream>>>(elist, rs, s2S, s2D, h2h, b2, Wc, bc, out, N);
}

// Round 4
// 245.201 us; speedup vs baseline: 5.3210x; 1.6780x over previous
//
#include <hip/hip_runtime.h>
#include <hip/hip_fp16.h>
#include <math.h>

#define F_IN 128
#define C1 256   // HEADS*HID
#define NH1 4
#define C2 64
#define SCAN_CHUNK 512

typedef __attribute__((ext_vector_type(8))) _Float16 f16x8;
typedef __attribute__((ext_vector_type(4))) float f32x4;

__device__ __forceinline__ float lrelu(float x) { return x >= 0.f ? x : 0.2f * x; }
__device__ __forceinline__ float elu(float x) { return x > 0.f ? x : expm1f(x); }

struct __align__(8) H4 { __half2 a, b; };

// ---------------- CSR build ----------------
__global__ void k_count(const int* __restrict__ edst, int* __restrict__ cnt, int E, int N) {
    int e = blockIdx.x * blockDim.x + threadIdx.x;
    int ET = E + N;
    if (e >= ET) return;
    int d = (e < E) ? edst[e] : (e - E);
    atomicAdd(&cnt[d], 1);
}

__global__ __launch_bounds__(SCAN_CHUNK) void k_scan_a(const int* __restrict__ cnt,
                                                        int* __restrict__ rs,
                                                        int* __restrict__ bsum, int N) {
    __shared__ int tmp[SCAN_CHUNK];
    int base = blockIdx.x * SCAN_CHUNK;
    int t = threadIdx.x;
    int v = (base + t < N) ? cnt[base + t] : 0;
    tmp[t] = v;
    __syncthreads();
    for (int off = 1; off < SCAN_CHUNK; off <<= 1) {
        int add = (t >= off) ? tmp[t - off] : 0;
        __syncthreads();
        tmp[t] += add;
        __syncthreads();
    }
    if (base + t < N) rs[base + t] = tmp[t] - v;  // exclusive within block
    if (t == SCAN_CHUNK - 1) bsum[blockIdx.x] = tmp[t];
}

// parallel block-sum exclusive scan (nb <= 512)
__global__ __launch_bounds__(512) void k_scan_b(int* __restrict__ bsum, int nb,
                                                int* __restrict__ total_out) {
    __shared__ int tmp[512];
    int t = threadIdx.x;
    int v = (t < nb) ? bsum[t] : 0;
    tmp[t] = v;
    __syncthreads();
    for (int off = 1; off < 512; off <<= 1) {
        int add = (t >= off) ? tmp[t - off] : 0;
        __syncthreads();
        tmp[t] += add;
        __syncthreads();
    }
    if (t < nb) bsum[t] = tmp[t] - v;
    if (t == 511) *total_out = tmp[511];
}

__global__ void k_scan_c(int* __restrict__ rs, const int* __restrict__ bsum, int N) {
    int i = blockIdx.x * blockDim.x + threadIdx.x;
    if (i < N) rs[i] += bsum[i / SCAN_CHUNK];
}

__global__ void k_scatter(const int* __restrict__ esrc, const int* __restrict__ edst,
                          const int* __restrict__ rs, int* __restrict__ cursor,
                          int* __restrict__ elist, int E, int N) {
    int e = blockIdx.x * blockDim.x + threadIdx.x;
    int ET = E + N;
    if (e >= ET) return;
    int s, d;
    if (e < E) { s = esrc[e]; d = edst[e]; } else { s = d = e - E; }
    int pos = atomicAdd(&cursor[d], 1);
    elist[rs[d] + pos] = s;
}

// ---------------- weight prep: fp32 -> fp16 transposed ----------------
// W1 [128][256] -> W1T [256][128]; W2 [256][64] -> W2T [64][256]
__global__ void k_prep(const float* __restrict__ W1, const float* __restrict__ W2,
                       __half* __restrict__ W1T, __half* __restrict__ W2T) {
    int tid = blockIdx.x * 256 + threadIdx.x;
    if (tid < F_IN * C1) {
        int k = tid >> 8, n = tid & 255;
        W1T[n * F_IN + k] = __float2half(W1[tid]);
    }
    int t2 = tid - F_IN * C1;
    if (t2 >= 0 && t2 < C1 * C2) {
        int k = t2 >> 6, n = t2 & 63;
        W2T[n * C1 + k] = __float2half(W2[t2]);
    }
}

// ---------------- layer 1 GEMM: MFMA f16, fused scores ----------------
// 64 rows/block, N=256 in two 128-col halves. 4 waves, wave -> 16 rows.
__global__ __launch_bounds__(256) void k_gemm1(const float* __restrict__ x,
                                               const __half* __restrict__ W1T,
                                               const float* __restrict__ aS,
                                               const float* __restrict__ aD,
                                               __half* __restrict__ h1h,
                                               float* __restrict__ sS,
                                               float* __restrict__ sD, int N) {
    __shared__ __align__(16) __half As[64 * 128];   // [row][k] f16, 16B-granule XOR swizzle
    __shared__ __align__(16) __half Bs[128 * 128];  // [n][k] f16 (one col-half), swizzled
    int t = threadIdx.x;
    int rowBase = blockIdx.x * 64;
    // stage A (fp32 -> fp16, swizzled): thread t -> row t>>2, k-chunk (t&3)*32
    {
        int r = t >> 2, q = (t & 3) * 32;
        int row = rowBase + r;
        const float4* src = (const float4*)(x + (size_t)row * F_IN + q);
#pragma unroll
        for (int gg = 0; gg < 4; ++gg) {
            float4 v0 = {0.f,0.f,0.f,0.f}, v1 = {0.f,0.f,0.f,0.f};
            if (row < N) { v0 = src[gg * 2]; v1 = src[gg * 2 + 1]; }
            int gs = ((q >> 3) + gg) ^ (r & 7);
            __half2* dst = (__half2*)&As[r * 128 + gs * 8];
            dst[0] = __floats2half2_rn(v0.x, v0.y);
            dst[1] = __floats2half2_rn(v0.z, v0.w);
            dst[2] = __floats2half2_rn(v1.x, v1.y);
            dst[3] = __floats2half2_rn(v1.z, v1.w);
        }
    }
    int lane = t & 63, wv = t >> 6;
    int lm = lane & 15, lk = lane >> 4;
    int rA = wv * 16 + lm;
    int row = rowBase + rA;
    float ps[4] = {0,0,0,0}, pd[4] = {0,0,0,0};
    for (int nh = 0; nh < 2; ++nh) {
        __syncthreads();   // A-stage (first iter) / prior compute (second) complete
        {   // stage B half: rows nh*128..+127 of W1T
            int r = t & 127, gb = (t >> 7) * 8;
            const uint4* src = (const uint4*)(W1T + (size_t)(nh * 128 + r) * F_IN);
#pragma unroll
            for (int j = 0; j < 8; ++j) {
                int g = gb + j;
                int gs = g ^ (r & 7);
                *(uint4*)&Bs[r * 128 + gs * 8] = src[g];
            }
        }
        __syncthreads();
        f32x4 acc[8];
#pragma unroll
        for (int nt = 0; nt < 8; ++nt) acc[nt] = f32x4{0.f,0.f,0.f,0.f};
#pragma unroll
        for (int kt = 0; kt < 4; ++kt) {
            int g = kt * 4 + lk;
            int gs = (g ^ (lm & 7)) * 8;
            f16x8 af = *(const f16x8*)&As[rA * 128 + gs];
#pragma unroll
            for (int nt = 0; nt < 8; ++nt) {
                int rB = nt * 16 + lm;
                f16x8 bf = *(const f16x8*)&Bs[rB * 128 + gs];
                // swapped operands: lane holds out row=lm, cols lk*4+reg
                acc[nt] = __builtin_amdgcn_mfma_f32_16x16x32_f16(bf, af, acc[nt], 0, 0, 0);
            }
        }
#pragma unroll
        for (int nt = 0; nt < 8; ++nt) {
            int cbase = nh * 128 + nt * 16 + lk * 4;
            int h = cbase >> 6;
            float a0 = acc[nt][0], a1 = acc[nt][1], a2 = acc[nt][2], a3 = acc[nt][3];
            float4 s4 = *(const float4*)(aS + cbase);
            float4 d4 = *(const float4*)(aD + cbase);
            ps[h] += a0 * s4.x + a1 * s4.y + a2 * s4.z + a3 * s4.w;
            pd[h] += a0 * d4.x + a1 * d4.y + a2 * d4.z + a3 * d4.w;
            if (row < N) {
                H4 hv;
                hv.a = __floats2half2_rn(a0, a1);
                hv.b = __floats2half2_rn(a2, a3);
                *(H4*)(h1h + (size_t)row * C1 + cbase) = hv;
            }
        }
    }
#pragma unroll
    for (int h = 0; h < 4; ++h) {
        ps[h] += __shfl_xor(ps[h], 16, 64); ps[h] += __shfl_xor(ps[h], 32, 64);
        pd[h] += __shfl_xor(pd[h], 16, 64); pd[h] += __shfl_xor(pd[h], 32, 64);
    }
    if (lk == 0 && row < N) {
#pragma unroll
        for (int h = 0; h < 4; ++h) { sS[row * 4 + h] = ps[h]; sD[row * 4 + h] = pd[h]; }
    }
}

// one wave per dst node; lane covers 4 channels; 4-deep pipelined gathers.
__global__ __launch_bounds__(256) void k_aggr1(const int* __restrict__ elist,
                                               const int* __restrict__ rs,
                                               const float* __restrict__ sS,
                                               const float* __restrict__ sD,
                                               const __half* __restrict__ h1h,
                                               const float* __restrict__ b1,
                                               __half* __restrict__ o1h, int N) {
    int d = blockIdx.x * 4 + (threadIdx.x >> 6);
    if (d >= N) return;
    int lane = threadIdx.x & 63;
    int h = lane >> 4;
    float sdh = sD[d * 4 + h];
    int beg = rs[d], end = rs[d + 1];
    float4 acc = {0.f, 0.f, 0.f, 0.f};
    float den = 0.f;
    int i = beg;
    for (; i + 4 <= end; i += 4) {
        int s0 = elist[i], s1 = elist[i + 1], s2 = elist[i + 2], s3 = elist[i + 3];
        H4 r0 = *(const H4*)(h1h + (size_t)s0 * C1 + lane * 4);
        H4 r1 = *(const H4*)(h1h + (size_t)s1 * C1 + lane * 4);
        H4 r2 = *(const H4*)(h1h + (size_t)s2 * C1 + lane * 4);
        H4 r3 = *(const H4*)(h1h + (size_t)s3 * C1 + lane * 4);
        float w0 = __expf(lrelu(sS[s0 * 4 + h] + sdh));
        float w1 = __expf(lrelu(sS[s1 * 4 + h] + sdh));
        float w2 = __expf(lrelu(sS[s2 * 4 + h] + sdh));
        float w3 = __expf(lrelu(sS[s3 * 4 + h] + sdh));
        den += (w0 + w1) + (w2 + w3);
        float2 f;
        f = __half22float2(r0.a); acc.x += w0 * f.x; acc.y += w0 * f.y;
        f = __half22float2(r0.b); acc.z += w0 * f.x; acc.w += w0 * f.y;
        f = __half22float2(r1.a); acc.x += w1 * f.x; acc.y += w1 * f.y;
        f = __half22float2(r1.b); acc.z += w1 * f.x; acc.w += w1 * f.y;
        f = __half22float2(r2.a); acc.x += w2 * f.x; acc.y += w2 * f.y;
        f = __half22float2(r2.b); acc.z += w2 * f.x; acc.w += w2 * f.y;
        f = __half22float2(r3.a); acc.x += w3 * f.x; acc.y += w3 * f.y;
        f = __half22float2(r3.b); acc.z += w3 * f.x; acc.w += w3 * f.y;
    }
    for (; i < end; ++i) {
        int s0 = elist[i];
        H4 r0 = *(const H4*)(h1h + (size_t)s0 * C1 + lane * 4);
        float w0 = __expf(lrelu(sS[s0 * 4 + h] + sdh));
        den += w0;
        float2 f;
        f = __half22float2(r0.a); acc.x += w0 * f.x; acc.y += w0 * f.y;
        f = __half22float2(r0.b); acc.z += w0 * f.x; acc.w += w0 * f.y;
    }
    float inv = 1.f / (den + 1e-16f);
    float4 bb = *(const float4*)(b1 + lane * 4);
    H4 o;
    o.a = __floats2half2_rn(elu(acc.x * inv + bb.x), elu(acc.y * inv + bb.y));
    o.b = __floats2half2_rn(elu(acc.z * inv + bb.z), elu(acc.w * inv + bb.w));
    *(H4*)(o1h + (size_t)d * C1 + lane * 4) = o;
}

// ---------------- layer 2 GEMM: MFMA f16, fused scores ----------------
// 64 rows/block, K=256 in two halves, N=64. 4 waves.
__global__ __launch_bounds__(256) void k_gemm2(const __half* __restrict__ o1h,
                                               const __half* __restrict__ W2T,
                                               const float* __restrict__ aS,
                                               const float* __restrict__ aD,
                                               __half* __restrict__ h2h,
                                               float* __restrict__ sS,
                                               float* __restrict__ sD, int N) {
    __shared__ __align__(16) __half As[64 * 128];   // [row][k-half] swizzled
    __shared__ __align__(16) __half Bs[64 * 256];   // [n][k] full, swizzled (low-3 granule bits)
    int t = threadIdx.x;
    int rowBase = blockIdx.x * 64;
    {   // stage B full: thread t -> n = t&63, granules (t>>6)*8..+7
        int n = t & 63, gb = (t >> 6) * 8;
        const uint4* src = (const uint4*)(W2T + (size_t)n * C1);
#pragma unroll
        for (int j = 0; j < 8; ++j) {
            int g = gb + j;
            int gs = (g & ~7) | ((g & 7) ^ (n & 7));
            *(uint4*)&Bs[n * 256 + gs * 8] = src[g];
        }
    }
    int lane = t & 63, wv = t >> 6;
    int lm = lane & 15, lk = lane >> 4;
    int rA = wv * 16 + lm;
    int row = rowBase + rA;
    f32x4 acc[4];
#pragma unroll
    for (int nt = 0; nt < 4; ++nt) acc[nt] = f32x4{0.f,0.f,0.f,0.f};
    for (int kh = 0; kh < 2; ++kh) {
        __syncthreads();
        {   // stage A k-half (fp16 direct copy, swizzled)
            int r = t >> 2, q = (t & 3) * 32;
            int grow = rowBase + r;
            const uint4* src = (const uint4*)(o1h + (size_t)grow * C1 + kh * 128 + q);
#pragma unroll
            for (int gg = 0; gg < 4; ++gg) {
                uint4 v = {0, 0, 0, 0};
                if (grow < N) v = src[gg];
                int gs = ((q >> 3) + gg) ^ (r & 7);
                *(uint4*)&As[r * 128 + gs * 8] = v;
            }
        }
        __syncthreads();
#pragma unroll
        for (int kt = 0; kt < 4; ++kt) {
            int g = kt * 4 + lk;
            f16x8 af = *(const f16x8*)&As[rA * 128 + (g ^ (lm & 7)) * 8];
            int gB = kh * 16 + g;
            int gBs = (gB & ~7) | ((gB & 7) ^ (lm & 7));
#pragma unroll
            for (int nt = 0; nt < 4; ++nt) {
                int rB = nt * 16 + lm;
                f16x8 bf = *(const f16x8*)&Bs[rB * 256 + gBs * 8];
                acc[nt] = __builtin_amdgcn_mfma_f32_16x16x32_f16(bf, af, acc[nt], 0, 0, 0);
            }
        }
    }
    float ps = 0.f, pd = 0.f;
#pragma unroll
    for (int nt = 0; nt < 4; ++nt) {
        int cbase = nt * 16 + lk * 4;
        float a0 = acc[nt][0], a1 = acc[nt][1], a2 = acc[nt][2], a3 = acc[nt][3];
        float4 s4 = *(const float4*)(aS + cbase);
        float4 d4 = *(const float4*)(aD + cbase);
        ps += a0 * s4.x + a1 * s4.y + a2 * s4.z + a3 * s4.w;
        pd += a0 * d4.x + a1 * d4.y + a2 * d4.z + a3 * d4.w;
        if (row < N) {
            H4 hv;
            hv.a = __floats2half2_rn(a0, a1);
            hv.b = __floats2half2_rn(a2, a3);
            *(H4*)(h2h + (size_t)row * C2 + cbase) = hv;
        }
    }
    ps += __shfl_xor(ps, 16, 64); ps += __shfl_xor(ps, 32, 64);
    pd += __shfl_xor(pd, 16, 64); pd += __shfl_xor(pd, 32, 64);
    if (lk == 0 && row < N) { sS[row] = ps; sD[row] = pd; }
}

// one wave per dst node, 2 edges per iteration (half-wave each), 2-deep unroll.
__global__ __launch_bounds__(256) void k_aggr2(const int* __restrict__ elist,
                                               const int* __restrict__ rs,
                                               const float* __restrict__ sS,
                                               const float* __restrict__ sD,
                                               const __half* __restrict__ h2h,
                                               const float* __restrict__ b2,
                                               const float* __restrict__ Wc,
                                               const float* __restrict__ bc,
                                               float* __restrict__ out, int N) {
    int d = blockIdx.x * 4 + (threadIdx.x >> 6);
    if (d >= N) return;
    int lane = threadIdx.x & 63;
    int half = lane >> 5, c2 = lane & 31;   // channels 2*c2, 2*c2+1
    float sdd = sD[d];
    int beg = rs[d], end = rs[d + 1];
    float2 acc = {0.f, 0.f};
    float den = 0.f;
    int i = beg;
    for (; i + 4 <= end; i += 4) {
        int sA = elist[i + half];
        int sB = elist[i + 2 + half];
        float2 ra = __half22float2(*(const __half2*)(h2h + (size_t)sA * C2 + c2 * 2));
        float2 rb = __half22float2(*(const __half2*)(h2h + (size_t)sB * C2 + c2 * 2));
        float wa = __expf(lrelu(sS[sA] + sdd));
        float wb = __expf(lrelu(sS[sB] + sdd));
        den += wa + wb;
        acc.x += wa * ra.x + wb * rb.x;
        acc.y += wa * ra.y + wb * rb.y;
    }
    if (i + 2 <= end) {
        int sA = elist[i + half];
        float2 ra = __half22float2(*(const __half2*)(h2h + (size_t)sA * C2 + c2 * 2));
        float wa = __expf(lrelu(sS[sA] + sdd));
        den += wa;
        acc.x += wa * ra.x;
        acc.y += wa * ra.y;
        i += 2;
    }
    if (i < end && half == 0) {
        int sA = elist[i];
        float2 ra = __half22float2(*(const __half2*)(h2h + (size_t)sA * C2 + c2 * 2));
        float wa = __expf(lrelu(sS[sA] + sdd));
        den += wa;
        acc.x += wa * ra.x;
        acc.y += wa * ra.y;
    }
    // merge the two halves
    acc.x += __shfl_xor(acc.x, 32, 64);
    acc.y += __shfl_xor(acc.y, 32, 64);
    den   += __shfl_xor(den, 32, 64);
    float inv = 1.f / (den + 1e-16f);
    float vx = acc.x * inv + b2[c2 * 2];
    float vy = acc.y * inv + b2[c2 * 2 + 1];
    float4 wc = *(const float4*)(Wc + c2 * 4);
    float p0 = vx * wc.x + vy * wc.z;
    float p1 = vx * wc.y + vy * wc.w;
    for (int off = 16; off; off >>= 1) {
        p0 += __shfl_down(p0, off, 32);
        p1 += __shfl_down(p1, off, 32);
    }
    if (lane == 0) { out[d * 2 + 0] = p0 + bc[0]; out[d * 2 + 1] = p1 + bc[1]; }
}

extern "C" void kernel_launch(void* const* d_in, const int* in_sizes, int n_in,
                              void* d_out, int out_size, void* d_ws, size_t ws_size,
                              hipStream_t stream) {
    const float* x   = (const float*)d_in[0];
    const int*   ei  = (const int*)d_in[1];
    const float* W1  = (const float*)d_in[2];
    const float* aS1 = (const float*)d_in[3];
    const float* aD1 = (const float*)d_in[4];
    const float* b1  = (const float*)d_in[5];
    const float* W2  = (const float*)d_in[6];
    const float* aS2 = (const float*)d_in[7];
    const float* aD2 = (const float*)d_in[8];
    const float* b2  = (const float*)d_in[9];
    const float* Wc  = (const float*)d_in[10];
    const float* bc  = (const float*)d_in[11];
    float* out = (float*)d_out;

    int N = in_sizes[0] / F_IN;
    int E = in_sizes[1] / 2;
    const int* esrc = ei;
    const int* edst = ei + E;
    int ET = E + N;
    int nb = (N + SCAN_CHUNK - 1) / SCAN_CHUNK;

    char* p = (char*)d_ws;
    __half* h1h = (__half*)p; p += (size_t)N * C1 * sizeof(__half);
    __half* o1h = (__half*)p; p += (size_t)N * C1 * sizeof(__half);
    __half* h2h = (__half*)p; p += (size_t)N * C2 * sizeof(__half);
    __half* W1T = (__half*)p; p += (size_t)C1 * F_IN * sizeof(__half);
    __half* W2T = (__half*)p; p += (size_t)C2 * C1 * sizeof(__half);
    float* s1S  = (float*)p;  p += (size_t)N * NH1 * sizeof(float);
    float* s1D  = (float*)p;  p += (size_t)N * NH1 * sizeof(float);
    float* s2S  = (float*)p;  p += (size_t)N * sizeof(float);
    float* s2D  = (float*)p;  p += (size_t)N * sizeof(float);
    int* cnt    = (int*)p;    p += (size_t)N * sizeof(int);
    int* cursor = (int*)p;    p += (size_t)N * sizeof(int);
    int* rs     = (int*)p;    p += (size_t)(N + 1) * sizeof(int);
    int* bsum   = (int*)p;    p += (size_t)nb * sizeof(int);
    int* elist  = (int*)p;    p += (size_t)ET * sizeof(int);

    // CSR build (shared by both layers)
    hipMemsetAsync(cnt, 0, (size_t)2 * N * 4, stream);   // cnt + cursor (contiguous)
    k_count<<<(ET + 255) / 256, 256, 0, stream>>>(edst, cnt, E, N);
    k_scan_a<<<nb, SCAN_CHUNK, 0, stream>>>(cnt, rs, bsum, N);
    k_scan_b<<<1, 512, 0, stream>>>(bsum, nb, rs + N);
    k_scan_c<<<(N + 255) / 256, 256, 0, stream>>>(rs, bsum, N);
    k_scatter<<<(ET + 255) / 256, 256, 0, stream>>>(esrc, edst, rs, cursor, elist, E, N);

    // weight prep
    k_prep<<<(F_IN * C1 + C1 * C2 + 255) / 256, 256, 0, stream>>>(W1, W2, W1T, W2T);

    // layer 1
    k_gemm1<<<(N + 63) / 64, 256, 0, stream>>>(x, W1T, aS1, aD1, h1h, s1S, s1D, N);
    k_aggr1<<<(N + 3) / 4, 256, 0, stream>>>(elist, rs, s1S, s1D, h1h, b1, o1h, N);

    // layer 2 + classifier
    k_gemm2<<<(N + 63) / 64, 256, 0, stream>>>(o1h, W2T, aS2, aD2, h2h, s2S, s2D, N);
    k_aggr2<<<(N + 3) / 4, 256, 0, stream>>>(elist, rs, s2S, s2D, h2h, b2, Wc, bc, out, N);
}